// Round 4
// baseline (473.819 us; speedup 1.0000x reference)
//
#include <hip/hip_runtime.h>
#include <math.h>

// Round 12:
//  * mfma_gemm_v3: triple-buffered LDS + counted s_waitcnt vmcnt(4) + ONE raw
//    s_barrier per K-step (prefetch distance 2 K-tiles, never vmcnt(0) in
//    steady state). Race-free by construction: stages for tile t+2 overwrite
//    tile t-1's buffer, whose ds_reads drained before the previous barrier
//    (every read feeds an MFMA before that barrier).
//  * rope_norm_kernel_v3: one wave per (bh,l) row; rotate pair (d,d+64) is
//    lane-local (same cos/sin), no LDS, no barriers, DPP wave reduction.
//  * attention kernel v5 unchanged (round-11).

#define D 2048
#define NH 16
#define DH 128
#define BB 2
#define LL 2048
#define BHD (BB*NH)      // 32
#define MROWS (BB*LL)    // 4096
#define KDIM D

typedef __attribute__((ext_vector_type(8))) short short8;
typedef __attribute__((ext_vector_type(4))) float floatx4;

// fp32 -> bf16, round-to-nearest-even
__device__ __forceinline__ unsigned short f2bf(float f) {
    unsigned u = __float_as_uint(f);
    unsigned r = u + 0x7FFFu + ((u >> 16) & 1u);
    return (unsigned short)(r >> 16);
}
__device__ __forceinline__ float bf2f(unsigned short u) {
    return __uint_as_float(((unsigned)u) << 16);
}

// async global->LDS DMA, 16 B/lane; LDS dest is wave-uniform base + lane*16
__device__ __forceinline__ void async16(const void* g, void* lds) {
    __builtin_amdgcn_global_load_lds(
        (const __attribute__((address_space(1))) unsigned int*)g,
        (__attribute__((address_space(3))) unsigned int*)lds, 16, 0, 0);
}

// DPP lane-move within 16-lane rows (VALU-speed, no LDS pipe).
template<int CTRL>
__device__ __forceinline__ float dpp_movf(float x) {
    return __int_as_float(__builtin_amdgcn_update_dpp(
        0, __float_as_int(x), CTRL, 0xF, 0xF, true));
}
__device__ __forceinline__ float row_max16(float x) {
    x = fmaxf(x, dpp_movf<0xB1>(x));
    x = fmaxf(x, dpp_movf<0x4E>(x));
    x = fmaxf(x, dpp_movf<0x124>(x));
    x = fmaxf(x, dpp_movf<0x128>(x));
    return x;
}
__device__ __forceinline__ float row_sum16(float x) {
    x += dpp_movf<0xB1>(x);
    x += dpp_movf<0x4E>(x);
    x += dpp_movf<0x124>(x);
    x += dpp_movf<0x128>(x);
    return x;
}

// ---------------------------------------------------------------------------
// elementwise fp32 -> bf16 cast, float4-vectorized
// ---------------------------------------------------------------------------
__global__ __launch_bounds__(256)
void cast_bf16_kernel_v2(const float* __restrict__ in,
                         unsigned short* __restrict__ out, int n4)
{
    int i = blockIdx.x * 256 + threadIdx.x;
    if (i < n4) {
        float4 v = ((const float4*)in)[i];
        ushort4 o;
        o.x = f2bf(v.x); o.y = f2bf(v.y); o.z = f2bf(v.z); o.w = f2bf(v.w);
        ((ushort4*)out)[i] = o;
    }
}

// ---------------------------------------------------------------------------
// W (K x N fp32 row-major) -> Wt (N x K bf16 row-major), 32x32 LDS tiles
// ---------------------------------------------------------------------------
__global__ __launch_bounds__(256)
void transpose_cast_kernel_v2(const float* __restrict__ W,
                              unsigned short* __restrict__ Wt, int K, int N)
{
    __shared__ float tile[32][33];
    const int tx = threadIdx.x & 31, ty = threadIdx.x >> 5;  // ty in 0..7
    const int n0 = blockIdx.x * 32, k0 = blockIdx.y * 32;
#pragma unroll
    for (int r = 0; r < 4; r++)
        tile[ty + 8 * r][tx] = W[(size_t)(k0 + ty + 8 * r) * N + n0 + tx];
    __syncthreads();
#pragma unroll
    for (int r = 0; r < 4; r++)
        Wt[(size_t)(n0 + ty + 8 * r) * K + k0 + tx] = f2bf(tile[tx][ty + 8 * r]);
}

// ---------------------------------------------------------------------------
// V (bh, l, dh) -> Vt (bh, dh, l), bf16, 32x32 LDS tiles (+2B pad row)
// ---------------------------------------------------------------------------
__global__ __launch_bounds__(256)
void transpose_v_kernel_v2(const unsigned short* __restrict__ Vb,
                           unsigned short* __restrict__ VtG)
{
    __shared__ unsigned short tile[32][34];
    const int tx = threadIdx.x & 31, ty = threadIdx.x >> 5;
    const int l0 = blockIdx.x * 32, d0 = blockIdx.y * 32;
    const int bh = blockIdx.z;
    const unsigned short* src = Vb + (size_t)bh * LL * DH;
    unsigned short* dst = VtG + (size_t)bh * DH * LL;
#pragma unroll
    for (int r = 0; r < 4; r++)
        tile[ty + 8 * r][tx] = src[(size_t)(l0 + ty + 8 * r) * DH + d0 + tx];
    __syncthreads();
#pragma unroll
    for (int r = 0; r < 4; r++)
        dst[(size_t)(d0 + ty + 8 * r) * LL + l0 + tx] = tile[tx][ty + 8 * r];
}

// ---------------------------------------------------------------------------
// bf16 MFMA GEMM v3: C(MxN) = A(MxK) * Bt(NxK)^T. 128x128 tile, BK=32,
// 4 waves x 64x64 quadrant. Triple-buffered LDS, prefetch distance 2 tiles,
// one s_barrier + counted vmcnt(4) per K-step (vmcnt(0) only at the tail).
// MODE 0: fp32 store to C. MODE 1: bf16 scatter to Q/K/V in (B,H,L,Dh).
// ---------------------------------------------------------------------------
template<int N, int MODE>
__global__ __launch_bounds__(256)
void mfma_gemm_v3(const unsigned short* __restrict__ A,
                  const unsigned short* __restrict__ Bt,
                  float* __restrict__ C, unsigned short* __restrict__ Qo,
                  unsigned short* __restrict__ Ko, unsigned short* __restrict__ Vo)
{
    __shared__ unsigned short As[3][128 * 32];   // 3 x 8 KB
    __shared__ unsigned short Bs[3][128 * 32];   // 3 x 8 KB
    const int t = threadIdx.x;
    const int w = t >> 6, lane = t & 63;
    const int lrow = lane & 15, quad = lane >> 4;
    const int m0 = blockIdx.y * 128, n0 = blockIdx.x * 128;
    const int wm = (w >> 1) * 64, wn = (w & 1) * 64;

    floatx4 acc[4][4];
#pragma unroll
    for (int i = 0; i < 4; i++)
#pragma unroll
        for (int j = 0; j < 4; j++) acc[i][j] = (floatx4){0.f, 0.f, 0.f, 0.f};

    const int srow = 32 * w + (lane >> 2);
    const int sseg = (lane & 3) * 8;

    auto STAGE = [&](int k0, int buf) {
        async16(&A [(size_t)(m0 + srow)      * KDIM + k0 + sseg], &As[buf][(32 * w)      * 32]);
        async16(&A [(size_t)(m0 + srow + 16) * KDIM + k0 + sseg], &As[buf][(32 * w + 16) * 32]);
        async16(&Bt[(size_t)(n0 + srow)      * KDIM + k0 + sseg], &Bs[buf][(32 * w)      * 32]);
        async16(&Bt[(size_t)(n0 + srow + 16) * KDIM + k0 + sseg], &Bs[buf][(32 * w + 16) * 32]);
    };

    // prologue: tiles 0,1 staged; wait for tile 0 only (tile 1 stays in flight)
    STAGE(0, 0);
    STAGE(32, 1);
    asm volatile("s_waitcnt vmcnt(4)" ::: "memory");
    __builtin_amdgcn_s_barrier();
    __builtin_amdgcn_sched_barrier(0);

    int buf = 0;
    for (int k0 = 0; k0 < KDIM; k0 += 32) {
        // prefetch tile t+2 into the buffer vacated by tile t-1 (reads of
        // t-1 all drained before the previous barrier: each fed an MFMA)
        if (k0 + 64 < KDIM) {
            int nb = buf + 2; if (nb >= 3) nb -= 3;
            STAGE(k0 + 64, nb);
        }

        short8 a[4], b[4];
#pragma unroll
        for (int i = 0; i < 4; i++)
            a[i] = *(const short8*)&As[buf][(wm + i * 16 + lrow) * 32 + quad * 8];
#pragma unroll
        for (int j = 0; j < 4; j++)
            b[j] = *(const short8*)&Bs[buf][(wn + j * 16 + lrow) * 32 + quad * 8];
        __builtin_amdgcn_s_setprio(1);
#pragma unroll
        for (int i = 0; i < 4; i++)
#pragma unroll
            for (int j = 0; j < 4; j++)
                acc[i][j] = __builtin_amdgcn_mfma_f32_16x16x32_bf16(a[i], b[j], acc[i][j], 0, 0, 0);
        __builtin_amdgcn_s_setprio(0);

        if (k0 + 32 < KDIM) {
            if (k0 + 64 < KDIM)
                asm volatile("s_waitcnt vmcnt(4)" ::: "memory");  // t+1 landed
            else
                asm volatile("s_waitcnt vmcnt(0)" ::: "memory");  // tail
            __builtin_amdgcn_s_barrier();
            __builtin_amdgcn_sched_barrier(0);
        }
        buf = buf + 1; if (buf >= 3) buf -= 3;
    }

    // C/D fragment layout: col = lane&15, row = quad*4 + reg (m89-verified)
    if (MODE == 0) {
#pragma unroll
        for (int i = 0; i < 4; i++)
#pragma unroll
            for (int j = 0; j < 4; j++) {
                int col = n0 + wn + j * 16 + lrow;
#pragma unroll
                for (int r = 0; r < 4; r++) {
                    int m = m0 + wm + i * 16 + quad * 4 + r;
                    C[(size_t)m * N + col] = acc[i][j][r];
                }
            }
    } else {
        const int s = n0 >> 11;              // qkv slot, uniform per block
        const int h = (n0 & 2047) >> 7;
        unsigned short* dst = (s == 0) ? Qo : (s == 1) ? Ko : Vo;
#pragma unroll
        for (int i = 0; i < 4; i++)
#pragma unroll
            for (int j = 0; j < 4; j++) {
                int dh = wn + j * 16 + lrow;
#pragma unroll
                for (int r = 0; r < 4; r++) {
                    int m = m0 + wm + i * 16 + quad * 4 + r;
                    int b = m >> 11, l = m & 2047;
                    dst[(((size_t)b * NH + h) * LL + l) * DH + dh] = f2bf(acc[i][j][r]);
                }
            }
    }
}

// ---------------------------------------------------------------------------
// RoPE + L2-normalize v3: one 64-lane wave per (bh,l) row, handling Q and K.
// Rotate pair (d, d+64) shares cos/sin (angle depends on d&63), so each lane
// owns its pair in registers: no LDS, no barriers. Wave reduce via DPP+shfl.
// ---------------------------------------------------------------------------
__global__ __launch_bounds__(256)
void rope_norm_kernel_v3(unsigned short* __restrict__ Q,
                         unsigned short* __restrict__ K,
                         const float* __restrict__ s_qk_ptr)
{
    const int wid  = threadIdx.x >> 6;
    const int lane = threadIdx.x & 63;
    const int row  = blockIdx.x * 4 + wid;       // (bh*LL + l)
    const int l    = row & (LL - 1);
    const size_t base = (size_t)row * DH;

    // inv_freq = 10000^(-lane/64); ln(10000)/64 = 0.14391156831
    float ang = (float)l * expf(-0.14391157f * (float)lane);
    float c = cosf(ang), s = sinf(ang);

    float qlo = bf2f(Q[base + lane]), qhi = bf2f(Q[base + lane + 64]);
    float klo = bf2f(K[base + lane]), khi = bf2f(K[base + lane + 64]);

    // out = x*cos + rot(x)*sin ; rot = (-hi, lo) — same op order as v2
    float qr_lo = fmaf(qlo, c, (-qhi) * s);
    float qr_hi = fmaf(qhi, c,   qlo  * s);
    float kr_lo = fmaf(klo, c, (-khi) * s);
    float kr_hi = fmaf(khi, c,   klo  * s);

    float qs = qr_lo * qr_lo + qr_hi * qr_hi;
    float ks = kr_lo * kr_lo + kr_hi * kr_hi;
    qs = row_sum16(qs);  ks = row_sum16(ks);
    qs += __shfl_xor(qs, 16);  ks += __shfl_xor(ks, 16);
    qs += __shfl_xor(qs, 32);  ks += __shfl_xor(ks, 32);
    float qn = fmaxf(sqrtf(qs), 1e-12f);
    float kn = fmaxf(sqrtf(ks), 1e-12f);

    float sqk = s_qk_ptr[0];
    Q[base + lane]      = f2bf(qr_lo / qn * sqk);
    Q[base + lane + 64] = f2bf(qr_hi / qn * sqk);
    K[base + lane]      = f2bf(kr_lo / kn);
    K[base + lane + 64] = f2bf(kr_hi / kn);
}

// ---------------------------------------------------------------------------
// bf16 MFMA flash attention, causal (round-11 v5, unchanged):
//   BQ=128 per block, 4 waves x 32 q-rows; BK=64; dbuf K/V via async DMA
//   with XOR-swizzled layouts; DPP softmax; Ps swizzled; 80 KB LDS.
// ---------------------------------------------------------------------------
#define ABQ 128
#define ABK 64
__global__ __launch_bounds__(256, 2)
void attn_mfma_kernel_v5(const unsigned short* __restrict__ Q,
                         const unsigned short* __restrict__ K,
                         const unsigned short* __restrict__ Vt,
                         unsigned short* __restrict__ AOb)
{
    __shared__ __align__(16) unsigned short Ks[2][ABK * DH];   // 32 KB
    __shared__ __align__(16) unsigned short Vs[2][DH * ABK];   // 32 KB
    __shared__ __align__(16) unsigned short Ps[4][32][64];     // 16 KB swizzled

    const int t = threadIdx.x;
    const int w = t >> 6, lane = t & 63;
    const int lrow = lane & 15, quad = lane >> 4;
    const int bh = blockIdx.x;
    const int y  = blockIdx.y;
    const int qt = (y < 8) ? (15 - y) : (y - 8);   // pair-balanced mapping
    const int q0 = qt * ABQ;
    const int qw = q0 + w * 32;                    // wave's first q-row

    const unsigned short* Qb = Q  + (size_t)bh * LL * DH;
    const unsigned short* Kb = K  + (size_t)bh * LL * DH;
    const unsigned short* Vg = Vt + (size_t)bh * DH * LL;

    short8 aq[2][4];
#pragma unroll
    for (int h = 0; h < 2; h++)
#pragma unroll
        for (int kk = 0; kk < 4; kk++)
            aq[h][kk] = *(const short8*)&Qb[(size_t)(qw + 16 * h + lrow) * DH
                                            + kk * 32 + quad * 8];

    floatx4 oacc[2][8];
#pragma unroll
    for (int h = 0; h < 2; h++)
#pragma unroll
        for (int dt = 0; dt < 8; dt++) oacc[h][dt] = (floatx4){0.f, 0.f, 0.f, 0.f};
    float mrow[2][4], lsum[2][4];
#pragma unroll
    for (int h = 0; h < 2; h++)
#pragma unroll
        for (int r = 0; r < 4; r++) { mrow[h][r] = -1e30f; lsum[h][r] = 0.f; }

    auto STAGE = [&](int tile, int buf) {
        const int k0s = tile * ABK;
#pragma unroll
        for (int c = 0; c < 4; c++) {
            int row = 16 * w + 4 * c;
            int r   = row + (lane >> 4);
            int col = (lane & 15) ^ (r & 7);
            async16(&Kb[(size_t)(k0s + r) * DH + col * 8], &Ks[buf][row * DH]);
        }
#pragma unroll
        for (int c = 0; c < 4; c++) {
            int row = 32 * w + 8 * c;
            int r   = row + (lane >> 3);
            int col = (lane & 7) ^ (r & 7);
            async16(&Vg[(size_t)r * LL + k0s + col * 8], &Vs[buf][row * ABK]);
        }
    };

    const int ntiles = 2 * qt + 2;
    STAGE(0, 0);
    __syncthreads();

    int cur = 0;
    for (int tile = 0; tile < ntiles; tile++) {
        const int k0 = tile * ABK;
        if (tile + 1 < ntiles) STAGE(tile + 1, cur ^ 1);

        floatx4 sacc[2][4];
#pragma unroll
        for (int h = 0; h < 2; h++)
#pragma unroll
            for (int j = 0; j < 4; j++) sacc[h][j] = (floatx4){0.f, 0.f, 0.f, 0.f};
        __builtin_amdgcn_s_setprio(1);
#pragma unroll
        for (int kk = 0; kk < 4; kk++) {
#pragma unroll
            for (int j = 0; j < 4; j++) {
                int slot = (kk * 4 + quad) ^ (lrow & 7);
                short8 bk = *(const short8*)&Ks[cur][(j * 16 + lrow) * DH + slot * 8];
                sacc[0][j] = __builtin_amdgcn_mfma_f32_16x16x32_bf16(aq[0][kk], bk, sacc[0][j], 0, 0, 0);
                sacc[1][j] = __builtin_amdgcn_mfma_f32_16x16x32_bf16(aq[1][kk], bk, sacc[1][j], 0, 0, 0);
            }
        }
        __builtin_amdgcn_s_setprio(0);

#pragma unroll
        for (int h = 0; h < 2; h++) {
            if (k0 + ABK - 1 > qw + 16 * h) {
#pragma unroll
                for (int j = 0; j < 4; j++) {
                    int key = k0 + j * 16 + lrow;
#pragma unroll
                    for (int r = 0; r < 4; r++) {
                        int q = qw + 16 * h + quad * 4 + r;
                        if (key > q) sacc[h][j][r] = -1e30f;
                    }
                }
            }
        }

#pragma unroll
        for (int h = 0; h < 2; h++) {
            float alpha[4];
#pragma unroll
            for (int r = 0; r < 4; r++) {
                float mt = fmaxf(fmaxf(sacc[h][0][r], sacc[h][1][r]),
                                 fmaxf(sacc[h][2][r], sacc[h][3][r]));
                mt = row_max16(mt);
                float mn = fmaxf(mrow[h][r], mt);
                alpha[r] = __expf(mrow[h][r] - mn);
                mrow[h][r] = mn;
            }
#pragma unroll
            for (int r = 0; r < 4; r++) {
                int rowp = 16 * h + quad * 4 + r;
                float rs = 0.f;
#pragma unroll
                for (int j = 0; j < 4; j++) {
                    float p = __expf(sacc[h][j][r] - mrow[h][r]);
                    rs += p;
                    int slot = (2 * j + (lrow >> 3)) ^ (rowp & 7);
                    Ps[w][rowp][slot * 8 + (lrow & 7)] = f2bf(p);
                }
                rs = row_sum16(rs);
                lsum[h][r] = lsum[h][r] * alpha[r] + rs;
            }
#pragma unroll
            for (int dt = 0; dt < 8; dt++)
#pragma unroll
                for (int r = 0; r < 4; r++) oacc[h][dt][r] *= alpha[r];
        }

        __builtin_amdgcn_s_setprio(1);
#pragma unroll
        for (int kk2 = 0; kk2 < 2; kk2++) {
            int pslot = (kk2 * 4 + quad) ^ (lrow & 7);
            short8 pa0 = *(const short8*)&Ps[w][lrow][pslot * 8];
            short8 pa1 = *(const short8*)&Ps[w][16 + lrow][pslot * 8];
#pragma unroll
            for (int dt = 0; dt < 8; dt++) {
                int slot = (kk2 * 4 + quad) ^ (lrow & 7);
                short8 bv = *(const short8*)&Vs[cur][(dt * 16 + lrow) * ABK + slot * 8];
                oacc[0][dt] = __builtin_amdgcn_mfma_f32_16x16x32_bf16(pa0, bv, oacc[0][dt], 0, 0, 0);
                oacc[1][dt] = __builtin_amdgcn_mfma_f32_16x16x32_bf16(pa1, bv, oacc[1][dt], 0, 0, 0);
            }
        }
        __builtin_amdgcn_s_setprio(0);

        __syncthreads();
        cur ^= 1;
    }

    const int b = bh >> 4, hd = bh & 15;
#pragma unroll
    for (int h = 0; h < 2; h++)
#pragma unroll
        for (int r = 0; r < 4; r++) {
            float inv = 1.f / lsum[h][r];
            int q = qw + 16 * h + quad * 4 + r;
            size_t base = ((size_t)b * LL + q) * D + hd * DH;
#pragma unroll
            for (int dt = 0; dt < 8; dt++)
                AOb[base + dt * 16 + lrow] = f2bf(oacc[h][dt][r] * inv);
        }
}

// ---------------------------------------------------------------------------
extern "C" void kernel_launch(void* const* d_in, const int* in_sizes, int n_in,
                              void* d_out, int out_size, void* d_ws, size_t ws_size,
                              hipStream_t stream)
{
    const float* x     = (const float*)d_in[0];
    const float* w_qkv = (const float*)d_in[1];
    const float* w_out = (const float*)d_in[2];
    const float* s_qk  = (const float*)d_in[3];
    float* out = (float*)d_out;

    const size_t SZ = (size_t)BB * NH * LL * DH;   // 8388608 elements
    unsigned short* u = (unsigned short*)d_ws;
    unsigned short* xb    = u;                               // x bf16 -> later AO bf16
    unsigned short* wqkvT = xb    + (size_t)MROWS * KDIM;    // 6144 x 2048
    unsigned short* woutT = wqkvT + (size_t)(3 * D) * KDIM;  // 2048 x 2048
    unsigned short* Qb    = woutT + (size_t)D * KDIM;
    unsigned short* Kb    = Qb + SZ;
    unsigned short* Vb    = Kb + SZ;
    unsigned short* VtG   = Vb + SZ;

    // 1) x -> bf16
    cast_bf16_kernel_v2<<<(MROWS * KDIM / 4 + 255) / 256, 256, 0, stream>>>(
        x, xb, MROWS * KDIM / 4);
    // 2) w_qkv -> (3D x K) bf16
    transpose_cast_kernel_v2<<<dim3(3 * D / 32, KDIM / 32), 256, 0, stream>>>(
        w_qkv, wqkvT, KDIM, 3 * D);
    // 3) QKV projection, bf16 scatter into (B,H,L,Dh)
    mfma_gemm_v3<3 * D, 1><<<dim3(3 * D / 128, MROWS / 128), 256, 0, stream>>>(
        xb, wqkvT, nullptr, Qb, Kb, Vb);
    // 4) RoPE + normalize in place (+ s_qk into Q); one wave per row
    rope_norm_kernel_v3<<<dim3(BHD * LL / 4), 256, 0, stream>>>(Qb, Kb, s_qk);
    // 5) V -> V^T (bh, dh, l)
    transpose_v_kernel_v2<<<dim3(LL / 32, DH / 32, BHD), 256, 0, stream>>>(Vb, VtG);
    // 6) flash attention -> AO bf16 (B,L,D), reusing xb
    attn_mfma_kernel_v5<<<dim3(BHD, LL / ABQ), 256, 0, stream>>>(Qb, Kb, VtG, xb);
    // 7) w_out -> bf16
    transpose_cast_kernel_v2<<<dim3(D / 32, D / 32), 256, 0, stream>>>(
        w_out, woutT, D, D);
    // 8) output projection
    mfma_gemm_v3<D, 0><<<dim3(D / 128, MROWS / 128), 256, 0, stream>>>(
        xb, woutT, out, nullptr, nullptr, nullptr);
}

// Round 6
// 419.564 us; speedup vs baseline: 1.1293x; 1.1293x over previous
//
#include <hip/hip_runtime.h>
#include <math.h>

// Round 14 (resubmit of round 13 after infra "container failed twice"):
// identical semantics, kernel symbols renamed to change the source hash in
// case the failure is replayed from a hash-keyed cache.
//  * GEMM: exact round-3 m97-structure kernel (129 us QKV, MfmaUtil 35%).
//  * RoPE+norm: one wave per row, no LDS/barriers (round-12, ~ -38 us).
//  * Attention: round-11 BQ=128 dbuf+swizzle+DPP structure (~115 us).

#define D 2048
#define NH 16
#define DH 128
#define BB 2
#define LL 2048
#define BHD (BB*NH)      // 32
#define MROWS (BB*LL)    // 4096
#define KDIM D

typedef __attribute__((ext_vector_type(8))) short short8;
typedef __attribute__((ext_vector_type(4))) float floatx4;

// fp32 -> bf16 with round-to-nearest-even semantics
__device__ __forceinline__ unsigned short f2bf(float f) {
    unsigned u = __float_as_uint(f);
    unsigned r = u + 0x7FFFu + ((u >> 16) & 1u);
    return (unsigned short)(r >> 16);
}
__device__ __forceinline__ float bf2f(unsigned short u) {
    return __uint_as_float(((unsigned)u) << 16);
}

// async global->LDS DMA (16 B per lane); LDS dest = wave-uniform base + lane*16
__device__ __forceinline__ void async16(const void* g, void* lds) {
    __builtin_amdgcn_global_load_lds(
        (const __attribute__((address_space(1))) unsigned int*)g,
        (__attribute__((address_space(3))) unsigned int*)lds, 16, 0, 0);
}

// DPP lane-moves within 16-lane rows (VALU pipe, avoids ds_bpermute).
template<int CTRL>
__device__ __forceinline__ float dpp_movf(float x) {
    return __int_as_float(__builtin_amdgcn_update_dpp(
        0, __float_as_int(x), CTRL, 0xF, 0xF, true));
}
__device__ __forceinline__ float row_max16(float x) {
    x = fmaxf(x, dpp_movf<0xB1>(x));    // quad_perm xor1
    x = fmaxf(x, dpp_movf<0x4E>(x));    // quad_perm xor2
    x = fmaxf(x, dpp_movf<0x124>(x));   // row_ror:4
    x = fmaxf(x, dpp_movf<0x128>(x));   // row_ror:8
    return x;
}
__device__ __forceinline__ float row_sum16(float x) {
    x += dpp_movf<0xB1>(x);
    x += dpp_movf<0x4E>(x);
    x += dpp_movf<0x124>(x);
    x += dpp_movf<0x128>(x);
    return x;
}

// ---------------------------------------------------------------------------
// elementwise fp32 -> bf16 cast (float4 vectorized)
// ---------------------------------------------------------------------------
__global__ __launch_bounds__(256)
void cast_bf16_r14(const float* __restrict__ in,
                   unsigned short* __restrict__ out, int n4)
{
    int i = blockIdx.x * 256 + threadIdx.x;
    if (i < n4) {
        float4 v = ((const float4*)in)[i];
        ushort4 o;
        o.x = f2bf(v.x); o.y = f2bf(v.y); o.z = f2bf(v.z); o.w = f2bf(v.w);
        ((ushort4*)out)[i] = o;
    }
}

// ---------------------------------------------------------------------------
// W (K x N fp32 row-major) -> Wt (N x K bf16 row-major) via 32x32 LDS tile
// ---------------------------------------------------------------------------
__global__ __launch_bounds__(256)
void transpose_cast_r14(const float* __restrict__ W,
                        unsigned short* __restrict__ Wt, int K, int N)
{
    __shared__ float tile[32][33];
    const int tx = threadIdx.x & 31, ty = threadIdx.x >> 5;  // ty: 0..7
    const int n0 = blockIdx.x * 32, k0 = blockIdx.y * 32;
#pragma unroll
    for (int r = 0; r < 4; r++)
        tile[ty + 8 * r][tx] = W[(size_t)(k0 + ty + 8 * r) * N + n0 + tx];
    __syncthreads();
#pragma unroll
    for (int r = 0; r < 4; r++)
        Wt[(size_t)(n0 + ty + 8 * r) * K + k0 + tx] = f2bf(tile[tx][ty + 8 * r]);
}

// ---------------------------------------------------------------------------
// V (bh, l, dh) -> Vt (bh, dh, l), bf16, 32x32 LDS tile (+2B pad per row)
// ---------------------------------------------------------------------------
__global__ __launch_bounds__(256)
void transpose_v_r14(const unsigned short* __restrict__ Vb,
                     unsigned short* __restrict__ VtG)
{
    __shared__ unsigned short tile[32][34];
    const int tx = threadIdx.x & 31, ty = threadIdx.x >> 5;
    const int l0 = blockIdx.x * 32, d0 = blockIdx.y * 32;
    const int bh = blockIdx.z;
    const unsigned short* src = Vb + (size_t)bh * LL * DH;
    unsigned short* dst = VtG + (size_t)bh * DH * LL;
#pragma unroll
    for (int r = 0; r < 4; r++)
        tile[ty + 8 * r][tx] = src[(size_t)(l0 + ty + 8 * r) * DH + d0 + tx];
    __syncthreads();
#pragma unroll
    for (int r = 0; r < 4; r++)
        dst[(size_t)(d0 + ty + 8 * r) * LL + l0 + tx] = tile[tx][ty + 8 * r];
}

// ---------------------------------------------------------------------------
// bf16 MFMA GEMM (m97 structure): C(MxN) = A(MxK) * Bt(NxK)^T.
// 128x128 block tile, BK=32, 4 waves each owning a 64x64 quadrant.
// MODE 0: fp32 store to C. MODE 1: bf16 scatter into Q/K/V (B,H,L,Dh).
// ---------------------------------------------------------------------------
template<int N, int MODE>
__global__ __launch_bounds__(256)
void gemm_mfma_r14(const unsigned short* __restrict__ A,
                   const unsigned short* __restrict__ Bt,
                   float* __restrict__ C, unsigned short* __restrict__ Qo,
                   unsigned short* __restrict__ Ko, unsigned short* __restrict__ Vo)
{
    __shared__ unsigned short As[128 * 32];   // [m][k] contiguous (DMA order)
    __shared__ unsigned short Bs[128 * 32];   // [n][k] contiguous
    const int t = threadIdx.x;
    const int w = t >> 6, lane = t & 63;
    const int lrow = lane & 15, quad = lane >> 4;
    const int m0 = blockIdx.y * 128, n0 = blockIdx.x * 128;
    const int wm = (w >> 1) * 64, wn = (w & 1) * 64;

    floatx4 acc[4][4];
#pragma unroll
    for (int i = 0; i < 4; i++)
#pragma unroll
        for (int j = 0; j < 4; j++) acc[i][j] = (floatx4){0.f, 0.f, 0.f, 0.f};

    const int srow = 32 * w + (lane >> 2);
    const int sseg = (lane & 3) * 8;

    for (int k0 = 0; k0 < KDIM; k0 += 32) {
        __syncthreads();
        async16(&A [(size_t)(m0 + srow)      * KDIM + k0 + sseg], &As[(32 * w)      * 32]);
        async16(&A [(size_t)(m0 + srow + 16) * KDIM + k0 + sseg], &As[(32 * w + 16) * 32]);
        async16(&Bt[(size_t)(n0 + srow)      * KDIM + k0 + sseg], &Bs[(32 * w)      * 32]);
        async16(&Bt[(size_t)(n0 + srow + 16) * KDIM + k0 + sseg], &Bs[(32 * w + 16) * 32]);
        __syncthreads();

        short8 a[4], b[4];
#pragma unroll
        for (int i = 0; i < 4; i++)
            a[i] = *(const short8*)&As[(wm + i * 16 + lrow) * 32 + quad * 8];
#pragma unroll
        for (int j = 0; j < 4; j++)
            b[j] = *(const short8*)&Bs[(wn + j * 16 + lrow) * 32 + quad * 8];
#pragma unroll
        for (int i = 0; i < 4; i++)
#pragma unroll
            for (int j = 0; j < 4; j++)
                acc[i][j] = __builtin_amdgcn_mfma_f32_16x16x32_bf16(a[i], b[j], acc[i][j], 0, 0, 0);
    }

    // C/D fragment layout: col = lane&15, row = quad*4 + reg (m89-verified)
    if (MODE == 0) {
#pragma unroll
        for (int i = 0; i < 4; i++)
#pragma unroll
            for (int j = 0; j < 4; j++) {
                int col = n0 + wn + j * 16 + lrow;
#pragma unroll
                for (int r = 0; r < 4; r++) {
                    int m = m0 + wm + i * 16 + quad * 4 + r;
                    C[(size_t)m * N + col] = acc[i][j][r];
                }
            }
    } else {
        const int s = n0 >> 11;              // qkv slot (uniform per block)
        const int h = (n0 & 2047) >> 7;
        unsigned short* dst = (s == 0) ? Qo : (s == 1) ? Ko : Vo;
#pragma unroll
        for (int i = 0; i < 4; i++)
#pragma unroll
            for (int j = 0; j < 4; j++) {
                int dh = wn + j * 16 + lrow;
#pragma unroll
                for (int r = 0; r < 4; r++) {
                    int m = m0 + wm + i * 16 + quad * 4 + r;
                    int b = m >> 11, l = m & 2047;
                    dst[(((size_t)b * NH + h) * LL + l) * DH + dh] = f2bf(acc[i][j][r]);
                }
            }
    }
}

// ---------------------------------------------------------------------------
// RoPE + L2-normalize: one 64-lane wave per (bh,l) row, Q and K together.
// The rotate pair (d, d+64) shares cos/sin (angle depends on d&63 only), so
// each lane keeps its pair in registers: zero LDS, zero barriers.
// ---------------------------------------------------------------------------
__global__ __launch_bounds__(256)
void rope_norm_r14(unsigned short* __restrict__ Q,
                   unsigned short* __restrict__ K,
                   const float* __restrict__ s_qk_ptr)
{
    const int wid  = threadIdx.x >> 6;
    const int lane = threadIdx.x & 63;
    const int row  = blockIdx.x * 4 + wid;       // flattened (bh*LL + l)
    const int l    = row & (LL - 1);
    const size_t base = (size_t)row * DH;

    // inv_freq = 10000^(-lane/64); ln(10000)/64 = 0.14391156831
    float ang = (float)l * expf(-0.14391157f * (float)lane);
    float c = cosf(ang), s = sinf(ang);

    float qlo = bf2f(Q[base + lane]), qhi = bf2f(Q[base + lane + 64]);
    float klo = bf2f(K[base + lane]), khi = bf2f(K[base + lane + 64]);

    // out = x*cos + rot(x)*sin with rot = (-hi, lo) — same op order as before
    float qr_lo = fmaf(qlo, c, (-qhi) * s);
    float qr_hi = fmaf(qhi, c,   qlo  * s);
    float kr_lo = fmaf(klo, c, (-khi) * s);
    float kr_hi = fmaf(khi, c,   klo  * s);

    float qs = qr_lo * qr_lo + qr_hi * qr_hi;
    float ks = kr_lo * kr_lo + kr_hi * kr_hi;
    qs = row_sum16(qs);  ks = row_sum16(ks);
    qs += __shfl_xor(qs, 16);  ks += __shfl_xor(ks, 16);
    qs += __shfl_xor(qs, 32);  ks += __shfl_xor(ks, 32);
    float qn = fmaxf(sqrtf(qs), 1e-12f);
    float kn = fmaxf(sqrtf(ks), 1e-12f);

    float sqk = s_qk_ptr[0];
    Q[base + lane]      = f2bf(qr_lo / qn * sqk);
    Q[base + lane + 64] = f2bf(qr_hi / qn * sqk);
    K[base + lane]      = f2bf(kr_lo / kn);
    K[base + lane + 64] = f2bf(kr_hi / kn);
}

// ---------------------------------------------------------------------------
// bf16 MFMA flash attention, causal. BQ=128 per block (4 waves x 32 q-rows),
// BK=64. K/V double-buffered via async DMA with XOR-swizzled layouts; each
// Ks/Vs ds_read_b128 feeds two MFMAs; DPP softmax; Ps swizzled; 80 KB LDS.
// ---------------------------------------------------------------------------
#define ABQ 128
#define ABK 64
__global__ __launch_bounds__(256, 2)
void attn_mfma_r14(const unsigned short* __restrict__ Q,
                   const unsigned short* __restrict__ K,
                   const unsigned short* __restrict__ Vt,
                   unsigned short* __restrict__ AOb)
{
    __shared__ __align__(16) unsigned short Ks[2][ABK * DH];   // 32 KB
    __shared__ __align__(16) unsigned short Vs[2][DH * ABK];   // 32 KB
    __shared__ __align__(16) unsigned short Ps[4][32][64];     // 16 KB swizzled

    const int t = threadIdx.x;
    const int w = t >> 6, lane = t & 63;
    const int lrow = lane & 15, quad = lane >> 4;
    const int bh = blockIdx.x;
    const int y  = blockIdx.y;
    const int qt = (y < 8) ? (15 - y) : (y - 8);   // heavy+light pairing
    const int q0 = qt * ABQ;
    const int qw = q0 + w * 32;                    // wave's first q-row

    const unsigned short* Qb = Q  + (size_t)bh * LL * DH;
    const unsigned short* Kb = K  + (size_t)bh * LL * DH;
    const unsigned short* Vg = Vt + (size_t)bh * DH * LL;

    short8 aq[2][4];
#pragma unroll
    for (int h = 0; h < 2; h++)
#pragma unroll
        for (int kk = 0; kk < 4; kk++)
            aq[h][kk] = *(const short8*)&Qb[(size_t)(qw + 16 * h + lrow) * DH
                                            + kk * 32 + quad * 8];

    floatx4 oacc[2][8];
#pragma unroll
    for (int h = 0; h < 2; h++)
#pragma unroll
        for (int dt = 0; dt < 8; dt++) oacc[h][dt] = (floatx4){0.f, 0.f, 0.f, 0.f};
    float mrow[2][4], lsum[2][4];
#pragma unroll
    for (int h = 0; h < 2; h++)
#pragma unroll
        for (int r = 0; r < 4; r++) { mrow[h][r] = -1e30f; lsum[h][r] = 0.f; }

    auto STAGE = [&](int tile, int buf) {
        const int k0s = tile * ABK;
#pragma unroll
        for (int c = 0; c < 4; c++) {
            int row = 16 * w + 4 * c;
            int r   = row + (lane >> 4);
            int col = (lane & 15) ^ (r & 7);
            async16(&Kb[(size_t)(k0s + r) * DH + col * 8], &Ks[buf][row * DH]);
        }
#pragma unroll
        for (int c = 0; c < 4; c++) {
            int row = 32 * w + 8 * c;
            int r   = row + (lane >> 3);
            int col = (lane & 7) ^ (r & 7);
            async16(&Vg[(size_t)r * LL + k0s + col * 8], &Vs[buf][row * ABK]);
        }
    };

    const int ntiles = 2 * qt + 2;
    STAGE(0, 0);
    __syncthreads();

    int cur = 0;
    for (int tile = 0; tile < ntiles; tile++) {
        const int k0 = tile * ABK;
        if (tile + 1 < ntiles) STAGE(tile + 1, cur ^ 1);

        floatx4 sacc[2][4];
#pragma unroll
        for (int h = 0; h < 2; h++)
#pragma unroll
            for (int j = 0; j < 4; j++) sacc[h][j] = (floatx4){0.f, 0.f, 0.f, 0.f};
        __builtin_amdgcn_s_setprio(1);
#pragma unroll
        for (int kk = 0; kk < 4; kk++) {
#pragma unroll
            for (int j = 0; j < 4; j++) {
                int slot = (kk * 4 + quad) ^ (lrow & 7);
                short8 bk = *(const short8*)&Ks[cur][(j * 16 + lrow) * DH + slot * 8];
                sacc[0][j] = __builtin_amdgcn_mfma_f32_16x16x32_bf16(aq[0][kk], bk, sacc[0][j], 0, 0, 0);
                sacc[1][j] = __builtin_amdgcn_mfma_f32_16x16x32_bf16(aq[1][kk], bk, sacc[1][j], 0, 0, 0);
            }
        }
        __builtin_amdgcn_s_setprio(0);

#pragma unroll
        for (int h = 0; h < 2; h++) {
            if (k0 + ABK - 1 > qw + 16 * h) {
#pragma unroll
                for (int j = 0; j < 4; j++) {
                    int key = k0 + j * 16 + lrow;
#pragma unroll
                    for (int r = 0; r < 4; r++) {
                        int q = qw + 16 * h + quad * 4 + r;
                        if (key > q) sacc[h][j][r] = -1e30f;
                    }
                }
            }
        }

#pragma unroll
        for (int h = 0; h < 2; h++) {
            float alpha[4];
#pragma unroll
            for (int r = 0; r < 4; r++) {
                float mt = fmaxf(fmaxf(sacc[h][0][r], sacc[h][1][r]),
                                 fmaxf(sacc[h][2][r], sacc[h][3][r]));
                mt = row_max16(mt);
                float mn = fmaxf(mrow[h][r], mt);
                alpha[r] = __expf(mrow[h][r] - mn);
                mrow[h][r] = mn;
            }
#pragma unroll
            for (int r = 0; r < 4; r++) {
                int rowp = 16 * h + quad * 4 + r;
                float rs = 0.f;
#pragma unroll
                for (int j = 0; j < 4; j++) {
                    float p = __expf(sacc[h][j][r] - mrow[h][r]);
                    rs += p;
                    int slot = (2 * j + (lrow >> 3)) ^ (rowp & 7);
                    Ps[w][rowp][slot * 8 + (lrow & 7)] = f2bf(p);
                }
                rs = row_sum16(rs);
                lsum[h][r] = lsum[h][r] * alpha[r] + rs;
            }
#pragma unroll
            for (int dt = 0; dt < 8; dt++)
#pragma unroll
                for (int r = 0; r < 4; r++) oacc[h][dt][r] *= alpha[r];
        }

        __builtin_amdgcn_s_setprio(1);
#pragma unroll
        for (int kk2 = 0; kk2 < 2; kk2++) {
            int pslot = (kk2 * 4 + quad) ^ (lrow & 7);
            short8 pa0 = *(const short8*)&Ps[w][lrow][pslot * 8];
            short8 pa1 = *(const short8*)&Ps[w][16 + lrow][pslot * 8];
#pragma unroll
            for (int dt = 0; dt < 8; dt++) {
                int slot = (kk2 * 4 + quad) ^ (lrow & 7);
                short8 bv = *(const short8*)&Vs[cur][(dt * 16 + lrow) * ABK + slot * 8];
                oacc[0][dt] = __builtin_amdgcn_mfma_f32_16x16x32_bf16(pa0, bv, oacc[0][dt], 0, 0, 0);
                oacc[1][dt] = __builtin_amdgcn_mfma_f32_16x16x32_bf16(pa1, bv, oacc[1][dt], 0, 0, 0);
            }
        }
        __builtin_amdgcn_s_setprio(0);

        __syncthreads();
        cur ^= 1;
    }

    const int b = bh >> 4, hd = bh & 15;
#pragma unroll
    for (int h = 0; h < 2; h++)
#pragma unroll
        for (int r = 0; r < 4; r++) {
            float inv = 1.f / lsum[h][r];
            int q = qw + 16 * h + quad * 4 + r;
            size_t base = ((size_t)b * LL + q) * D + hd * DH;
#pragma unroll
            for (int dt = 0; dt < 8; dt++)
                AOb[base + dt * 16 + lrow] = f2bf(oacc[h][dt][r] * inv);
        }
}

// ---------------------------------------------------------------------------
extern "C" void kernel_launch(void* const* d_in, const int* in_sizes, int n_in,
                              void* d_out, int out_size, void* d_ws, size_t ws_size,
                              hipStream_t stream)
{
    const float* x     = (const float*)d_in[0];
    const float* w_qkv = (const float*)d_in[1];
    const float* w_out = (const float*)d_in[2];
    const float* s_qk  = (const float*)d_in[3];
    float* out = (float*)d_out;

    const size_t SZ = (size_t)BB * NH * LL * DH;   // 8388608 elements
    unsigned short* u = (unsigned short*)d_ws;
    unsigned short* xb    = u;                               // x bf16 -> later AO bf16
    unsigned short* wqkvT = xb    + (size_t)MROWS * KDIM;    // 6144 x 2048
    unsigned short* woutT = wqkvT + (size_t)(3 * D) * KDIM;  // 2048 x 2048
    unsigned short* Qb    = woutT + (size_t)D * KDIM;
    unsigned short* Kb    = Qb + SZ;
    unsigned short* Vb    = Kb + SZ;
    unsigned short* VtG   = Vb + SZ;

    // 1) x -> bf16
    cast_bf16_r14<<<(MROWS * KDIM / 4 + 255) / 256, 256, 0, stream>>>(
        x, xb, MROWS * KDIM / 4);
    // 2) w_qkv -> (3D x K) bf16
    transpose_cast_r14<<<dim3(3 * D / 32, KDIM / 32), 256, 0, stream>>>(
        w_qkv, wqkvT, KDIM, 3 * D);
    // 3) QKV projection, bf16 scatter into (B,H,L,Dh)
    gemm_mfma_r14<3 * D, 1><<<dim3(3 * D / 128, MROWS / 128), 256, 0, stream>>>(
        xb, wqkvT, nullptr, Qb, Kb, Vb);
    // 4) RoPE + normalize in place (+ s_qk into Q); one wave per row
    rope_norm_r14<<<dim3(BHD * LL / 4), 256, 0, stream>>>(Qb, Kb, s_qk);
    // 5) V -> V^T (bh, dh, l)
    transpose_v_r14<<<dim3(LL / 32, DH / 32, BHD), 256, 0, stream>>>(Vb, VtG);
    // 6) flash attention -> AO bf16 (B,L,D), reusing xb
    attn_mfma_r14<<<dim3(BHD, LL / ABQ), 256, 0, stream>>>(Qb, Kb, VtG, xb);
    // 7) w_out -> bf16
    transpose_cast_r14<<<dim3(D / 32, D / 32), 256, 0, stream>>>(
        w_out, woutT, D, D);
    // 8) output projection
    gemm_mfma_r14<D, 0><<<dim3(D / 128, MROWS / 128), 256, 0, stream>>>(
        xb, woutT, out, nullptr, nullptr, nullptr);
}